// Round 9
// baseline (260.836 us; speedup 1.0000x reference)
//
#include <hip/hip_runtime.h>
#include <hip/hip_bf16.h>

typedef __bf16 bf16x8 __attribute__((ext_vector_type(8)));
typedef __bf16 bf16x4 __attribute__((ext_vector_type(4)));
typedef float floatx4 __attribute__((ext_vector_type(4)));

typedef __attribute__((address_space(1))) const void gas_void;
typedef __attribute__((address_space(3))) void las_void;

__device__ inline void async_load16(const void* g, void* l) {
  __builtin_amdgcn_global_load_lds((gas_void*)g, (las_void*)l, 16, 0, 0);
}

// Fused preprocess: x->bf16 (blocks 0..2047), K->bf16 (2048..3071),
// V->Vt bf16 transpose (3072..4095), lsum zero (block 4096).
__global__ __launch_bounds__(256) void preprocess_kernel(
    const float* __restrict__ x, const float* __restrict__ Kp,
    const float* __restrict__ V, __bf16* __restrict__ xb,
    __bf16* __restrict__ Kb, __bf16* __restrict__ Vt,
    float* __restrict__ lsum) {
  const int b = blockIdx.x;
  const int t = threadIdx.x;
  if (b < 2048) {
#pragma unroll
    for (int k = 0; k < 4; ++k) {
      const int i = b * 1024 + k * 256 + t;
      float4 v = ((const float4*)x)[i];
      bf16x4 o = {(__bf16)v.x, (__bf16)v.y, (__bf16)v.z, (__bf16)v.w};
      ((bf16x4*)xb)[i] = o;
    }
  } else if (b < 3072) {
#pragma unroll
    for (int k = 0; k < 4; ++k) {
      const int i = (b - 2048) * 1024 + k * 256 + t;
      float4 v = ((const float4*)Kp)[i];
      bf16x4 o = {(__bf16)v.x, (__bf16)v.y, (__bf16)v.z, (__bf16)v.w};
      ((bf16x4*)Kb)[i] = o;
    }
  } else if (b < 4096) {
    __shared__ float tile[64][65];
    const int bb = b - 3072;
    const int bx = bb & 63, by = bb >> 6;
    for (int i = t; i < 64 * 64; i += 256) {
      const int r = i >> 6, c = i & 63;
      tile[r][c] = V[(size_t)(bx * 64 + r) * 1024 + by * 64 + c];
    }
    __syncthreads();
    for (int i = t; i < 64 * 64; i += 256) {
      const int r = i >> 6, c = i & 63;
      Vt[(size_t)(by * 64 + r) * 4096 + bx * 64 + c] = (__bf16)tile[c][r];
    }
  } else {
#pragma unroll
    for (int k = 0; k < 8; ++k)
      ((floatx4*)lsum)[k * 256 + t] = floatx4{0.f, 0.f, 0.f, 0.f};
  }
}

// C = A (MxK bf16, k-contig) x B (N rows of K bf16, k-contig). 128x128 tile, BK=64.
// STAGE 0: global_load_lds DMA staging (best for short-K, L2-resident operands:
//          GEMM1 measured 90.8 us r7 vs 107.4 us reg-staged r8).
// STAGE 1: register-staged pipeline — buffer_load tile k+1 into VGPRs during the
//          MFMA block; s_barrier only drains lgkm (best for long-K streaming:
//          GEMM2 ~25 us faster in r8).
// LDS: XOR-swizzled; 16-B unit (row m, k-chunk q in 0..7) at unit 8m + (q^(m&7)).
// Conflict-free both sides (r7: SQ_LDS_BANK_CONFLICT = 0).
// Flat-1D grid + XCD swizzle (id%8 = XCD): blocks sharing an A m-tile share an XCD.
// MODE 0: P = exp(min(dot/32,30)) -> bf16 Cb + fused row-sum atomicAdd into lsum.
// MODE 1: out = dot / lsum[m] -> fp32 Cf.
template <int MODE, int STAGE, int KS, int NS>
__global__ __launch_bounds__(256) void gemm_kernel(const __bf16* __restrict__ A,
                                                   const __bf16* __restrict__ B,
                                                   __bf16* __restrict__ Cb,
                                                   float* __restrict__ Cf,
                                                   float* __restrict__ lsum) {
  constexpr int BK = 64;
  __shared__ __bf16 As[128 * BK];  // 16 KiB
  __shared__ __bf16 Bs[128 * BK];  // 16 KiB
  const int t = threadIdx.x;
  const int lane = t & 63;
  const int w = t >> 6;
  const int wr = w >> 1, wc = w & 1;

  const int id = blockIdx.x;
  const int g = id & 7;
  const int s = id >> 3;
  const int mt = g * 8 + (s & 7);
  const int nt = s >> 3;
  const int m0 = mt * 128;
  const int n0 = nt * 128;

  const __bf16* Ab = A + (size_t)m0 * KS;
  const __bf16* Bb = B + (size_t)n0 * KS;

  floatx4 acc[4][4] = {};

  // staging: thread t -> rows r*32 + (t>>3), chunk (t&7)^((t>>3)&7)
  const int mA = t >> 3;
  const int qs = (t & 7) ^ (mA & 7);
  const __bf16* aP = Ab + (size_t)mA * KS + qs * 8;
  const __bf16* bP = Bb + (size_t)mA * KS + qs * 8;
  char* dA = (char*)As + t * 16;
  char* dB = (char*)Bs + t * 16;

  // fragment read offset (k-slice 0)
  const int rl = lane & 15;
  const int qq = lane >> 4;
  const int fo = rl * 128 + ((qq ^ (rl & 7)) << 4);

  bf16x8 sA[4], sB[4];
  if (STAGE == 1) {
#pragma unroll
    for (int r = 0; r < 4; ++r) {
      sA[r] = *(const bf16x8*)(aP + (size_t)r * 32 * KS);
      sB[r] = *(const bf16x8*)(bP + (size_t)r * 32 * KS);
    }
  }

  for (int k0 = 0; k0 < KS; k0 += BK) {
    if (STAGE == 0) {
#pragma unroll
      for (int r = 0; r < 4; ++r) {
        async_load16(aP + (size_t)r * 32 * KS + k0, dA + r * 4096);
        async_load16(bP + (size_t)r * 32 * KS + k0, dB + r * 4096);
      }
      __builtin_amdgcn_s_waitcnt(0);
      __syncthreads();
    } else {
#pragma unroll
      for (int r = 0; r < 4; ++r) {
        *(bf16x8*)(dA + r * 4096) = sA[r];
        *(bf16x8*)(dB + r * 4096) = sB[r];
      }
      __syncthreads();
      if (k0 + BK < KS) {
#pragma unroll
        for (int r = 0; r < 4; ++r) {
          sA[r] = *(const bf16x8*)(aP + (size_t)r * 32 * KS + k0 + BK);
          sB[r] = *(const bf16x8*)(bP + (size_t)r * 32 * KS + k0 + BK);
        }
      }
    }

    bf16x8 aF[4], bF[4];
#pragma unroll
    for (int i = 0; i < 4; ++i) {
      aF[i] = *(const bf16x8*)((const char*)As + wr * 8192 + i * 2048 + fo);
      bF[i] = *(const bf16x8*)((const char*)Bs + wc * 8192 + i * 2048 + fo);
    }
#pragma unroll
    for (int i = 0; i < 4; ++i)
#pragma unroll
      for (int j = 0; j < 4; ++j)
        acc[i][j] = __builtin_amdgcn_mfma_f32_16x16x32_bf16(aF[i], bF[j], acc[i][j], 0, 0, 0);
#pragma unroll
    for (int i = 0; i < 4; ++i) {
      aF[i] = *(const bf16x8*)((const char*)As + wr * 8192 + i * 2048 + (fo ^ 64));
      bF[i] = *(const bf16x8*)((const char*)Bs + wc * 8192 + i * 2048 + (fo ^ 64));
    }
#pragma unroll
    for (int i = 0; i < 4; ++i)
#pragma unroll
      for (int j = 0; j < 4; ++j)
        acc[i][j] = __builtin_amdgcn_mfma_f32_16x16x32_bf16(aF[i], bF[j], acc[i][j], 0, 0, 0);
    __syncthreads();
  }

  // C/D layout: col = lane&15, row = (lane>>4)*4 + reg
  const int cm = wr * 64 + ((lane >> 4) << 2);
  const int cn = wc * 64 + (lane & 15);
  if (MODE == 0) {
#pragma unroll
    for (int i = 0; i < 4; ++i)
#pragma unroll
      for (int r = 0; r < 4; ++r) {
        const int m = m0 + cm + i * 16 + r;
        float rs = 0.f;
#pragma unroll
        for (int j = 0; j < 4; ++j) {
          const float e = __expf(fminf(acc[i][j][r] * 0.03125f, 30.0f));
          rs += e;
          Cb[(size_t)m * NS + n0 + cn + j * 16] = (__bf16)e;
        }
        rs += __shfl_xor(rs, 1, 64);
        rs += __shfl_xor(rs, 2, 64);
        rs += __shfl_xor(rs, 4, 64);
        rs += __shfl_xor(rs, 8, 64);
        if ((lane & 15) == 0) atomicAdd(&lsum[m], rs);
      }
  } else {
#pragma unroll
    for (int i = 0; i < 4; ++i)
#pragma unroll
      for (int r = 0; r < 4; ++r) {
        const int m = m0 + cm + i * 16 + r;
        const float inv = 1.0f / lsum[m];
#pragma unroll
        for (int j = 0; j < 4; ++j)
          Cf[(size_t)m * NS + n0 + cn + j * 16] = acc[i][j][r] * inv;
      }
  }
}

extern "C" void kernel_launch(void* const* d_in, const int* in_sizes, int n_in,
                              void* d_out, int out_size, void* d_ws, size_t ws_size,
                              hipStream_t stream) {
  const float* x = (const float*)d_in[0];  // [8192][1024] fp32
  const float* K = (const float*)d_in[1];  // [4096][1024] fp32
  const float* V = (const float*)d_in[2];  // [4096][1024] fp32
  float* out = (float*)d_out;              // [8192][1024] fp32

  char* ws = (char*)d_ws;
  __bf16* xb = (__bf16*)ws;                        // 16 MiB
  __bf16* Kb = (__bf16*)(ws + (16u << 20));        // 8 MiB
  __bf16* Vt = (__bf16*)(ws + (24u << 20));        // 8 MiB
  __bf16* P  = (__bf16*)(ws + (32u << 20));        // 64 MiB
  float*  l  = (float*)(ws + (96u << 20));         // 32 KiB

  preprocess_kernel<<<4097, 256, 0, stream>>>(x, K, V, xb, Kb, Vt, l);
  // P = exp(xb @ Kb^T / 32), fused row sums (M=8192 N=4096 K=1024) — LDS-DMA staging
  gemm_kernel<0, 0, 1024, 4096><<<2048, 256, 0, stream>>>(xb, Kb, P, nullptr, l);
  // out = (P @ Vt-rows) / l (M=8192 N=1024 K=4096) — register-staged pipeline
  gemm_kernel<1, 1, 4096, 1024><<<512, 256, 0, stream>>>(P, Vt, nullptr, out, l);
}